// Round 2
// baseline (900.584 us; speedup 1.0000x reference)
//
#include <hip/hip_runtime.h>

// Problem constants
#define BB 64      // batch
#define SS 1024    // symbols (= values = d_model = 1024, all dims equal)
#define NN 1024    // generic K/N dim

// walk1[b,s] = mask[b] * SM[b, q[b], s]
__global__ void k_gather(const float* __restrict__ SM, const int* __restrict__ qidx,
                         const float* __restrict__ qmask, float* __restrict__ walk1) {
    int b = blockIdx.x;
    int q = qidx[b];
    float m = qmask[b];
    const float* row = SM + (size_t)b * SS * SS + (size_t)q * SS;
    int t = threadIdx.x * 4;
    float4 v = *(const float4*)(row + t);
    float* o = walk1 + b * SS + t;
    o[0] = m * v.x; o[1] = m * v.y; o[2] = m * v.z; o[3] = m * v.w;
}

// Unified vec-mat / skinny GEMM with K-split + atomic accumulate.
// C[r, t] += sum_k A[r, k] * W[r*mstride + k*NN + t]   (all fp32)
// ROWS rows per block share the same W (mstride==0 for shared weights).
// grid = (K/KC, nrows/ROWS), block = 256, each thread owns 4 contiguous t.
// REV=1: process row-blocks in reverse order (L3-residency heuristic for
// a second pass over a 256MB operand that just streamed through L3).
template<int ROWS, int KC, int REV>
__global__ __launch_bounds__(256) void k_vm(const float* __restrict__ A,
                                            const float* __restrict__ W,
                                            float* __restrict__ C,
                                            long mstride) {
    const int k0 = blockIdx.x * KC;
    const int by = REV ? (gridDim.y - 1 - blockIdx.y) : blockIdx.y;
    const int r0 = by * ROWS;
    __shared__ float As[ROWS * KC];
    for (int i = threadIdx.x; i < ROWS * KC; i += 256) {
        int r = i / KC, k = i % KC;
        As[i] = A[(r0 + r) * NN + k0 + k];
    }
    __syncthreads();

    const float* Wp = W + (size_t)r0 * mstride + (size_t)k0 * NN + threadIdx.x * 4;
    float acc[ROWS][4];
    #pragma unroll
    for (int r = 0; r < ROWS; ++r) {
        acc[r][0] = 0.f; acc[r][1] = 0.f; acc[r][2] = 0.f; acc[r][3] = 0.f;
    }

    for (int k = 0; k < KC; ++k) {
        float4 wv = *(const float4*)(Wp + (size_t)k * NN);
        #pragma unroll
        for (int r = 0; r < ROWS; ++r) {
            float a = As[r * KC + k];
            acc[r][0] = fmaf(a, wv.x, acc[r][0]);
            acc[r][1] = fmaf(a, wv.y, acc[r][1]);
            acc[r][2] = fmaf(a, wv.z, acc[r][2]);
            acc[r][3] = fmaf(a, wv.w, acc[r][3]);
        }
    }

    const int t = threadIdx.x * 4;
    #pragma unroll
    for (int r = 0; r < ROWS; ++r) {
        float* c = C + (size_t)(r0 + r) * NN + t;
        unsafeAtomicAdd(c + 0, acc[r][0]);
        unsafeAtomicAdd(c + 1, acc[r][1]);
        unsafeAtomicAdd(c + 2, acc[r][2]);
        unsafeAtomicAdd(c + 3, acc[r][3]);
    }
}

// Wsum[b,s] = walk1 + walk2 + walk3 + mask[b]*(s==q[b])
__global__ void k_wsum(const float* __restrict__ w1, const float* __restrict__ w2,
                       const float* __restrict__ w3, const int* __restrict__ qidx,
                       const float* __restrict__ qmask, float* __restrict__ Wsum) {
    int b = blockIdx.x;
    int q = qidx[b];
    float m = qmask[b];
    int t = threadIdx.x * 4;
    #pragma unroll
    for (int j = 0; j < 4; ++j) {
        int s = t + j;
        float v = w1[b * SS + s] + w2[b * SS + s] + w3[b * SS + s];
        if (s == q) v += m;
        Wsum[b * SS + s] = v;
    }
}

// In-place bias + tanh-approx GELU on h0 (y=0) / h1 (y=1)
__global__ void k_biasgelu(float* __restrict__ h0, float* __restrict__ h1,
                           const float* __restrict__ b0, const float* __restrict__ b1) {
    float* h = blockIdx.y ? h1 : h0;
    const float* bias = blockIdx.y ? b1 : b0;
    int b = blockIdx.x;
    int t = threadIdx.x * 4;
    #pragma unroll
    for (int j = 0; j < 4; ++j) {
        int d = t + j;
        float x = h[b * NN + d] + bias[d];
        float c = 0.7978845608028654f * (x + 0.044715f * x * x * x);
        h[b * NN + d] = 0.5f * x * (1.0f + tanhf(c));
    }
}

// d_out = src + bias; y=0: logits (offset 0), y=1: feedback (offset B*N)
__global__ void k_out(const float* __restrict__ lg, const float* __restrict__ fb,
                      const float* __restrict__ bo2, const float* __restrict__ bf2,
                      float* __restrict__ out) {
    int half = blockIdx.y;
    const float* src = half ? fb : lg;
    const float* bias = half ? bf2 : bo2;
    float* dst = out + (size_t)half * BB * NN;
    int b = blockIdx.x;
    int t = threadIdx.x * 4;
    #pragma unroll
    for (int j = 0; j < 4; ++j) {
        int n = t + j;
        dst[b * NN + n] = src[b * NN + n] + bias[n];
    }
}

extern "C" void kernel_launch(void* const* d_in, const int* in_sizes, int n_in,
                              void* d_out, int out_size, void* d_ws, size_t ws_size,
                              hipStream_t stream) {
    const float* MM   = (const float*)d_in[0];   // map_memory  [B,S,V]
    const float* SM   = (const float*)d_in[1];   // step_memory [B,S,S]
    const int*   qidx = (const int*)d_in[2];     // query_idx   [B]
    const float* qmask= (const float*)d_in[3];   // query_mask  [B]
    const float* sb   = (const float*)d_in[4];   // symbol_bank [S,D]
    const float* vb   = (const float*)d_in[5];   // value_bank  [V,D]
    const float* Wo1  = (const float*)d_in[6];
    const float* bo1  = (const float*)d_in[7];
    const float* Wo2  = (const float*)d_in[8];
    const float* bo2  = (const float*)d_in[9];
    const float* Wf1  = (const float*)d_in[10];
    const float* bf1  = (const float*)d_in[11];
    const float* Wf2  = (const float*)d_in[12];
    const float* bf2  = (const float*)d_in[13];
    float* out = (float*)d_out;

    float* ws    = (float*)d_ws;
    float* walk1 = ws;            // [64][1024] each
    float* walk2 = ws + 65536;
    float* walk3 = ws + 131072;
    float* Wsum  = ws + 196608;
    float* accv  = ws + 262144;
    float* gs    = ws + 327680;
    float* h_o   = ws + 393216;
    float* h_f   = ws + 458752;
    float* lg    = ws + 524288;
    float* fb    = ws + 589824;

    // zero all accumulators (ws is poisoned 0xAA before every call)
    hipMemsetAsync(d_ws, 0, 655360 * sizeof(float), stream);

    const long BSTRIDE = (long)SS * NN;   // batched matrix stride
    k_gather<<<BB, 256, 0, stream>>>(SM, qidx, qmask, walk1);
    // walk2 = walk1 @ SM[b] ; walk3 = walk2 @ SM[b]   (full SM passes)
    k_vm<1, 64, 0><<<dim3(16, BB), 256, 0, stream>>>(walk1, SM, walk2, BSTRIDE);
    k_vm<1, 64, 1><<<dim3(16, BB), 256, 0, stream>>>(walk2, SM, walk3, BSTRIDE);
    k_wsum<<<BB, 256, 0, stream>>>(walk1, walk2, walk3, qidx, qmask, Wsum);
    // acc_values = Wsum @ MM[b]   (full MM pass)
    k_vm<1, 64, 0><<<dim3(16, BB), 256, 0, stream>>>(Wsum, MM, accv, BSTRIDE);
    // graph_state = Wsum @ symbol_bank + acc_values @ value_bank (both atomic into gs)
    k_vm<8, 128, 0><<<dim3(8, 8), 256, 0, stream>>>(Wsum, sb, gs, 0L);
    k_vm<8, 128, 0><<<dim3(8, 8), 256, 0, stream>>>(accv, vb, gs, 0L);
    // MLPs
    k_vm<8, 128, 0><<<dim3(8, 8), 256, 0, stream>>>(gs, Wo1, h_o, 0L);
    k_vm<8, 128, 0><<<dim3(8, 8), 256, 0, stream>>>(gs, Wf1, h_f, 0L);
    k_biasgelu<<<dim3(BB, 2), 256, 0, stream>>>(h_o, h_f, bo1, bf1);
    k_vm<8, 128, 0><<<dim3(8, 8), 256, 0, stream>>>(h_o, Wo2, lg, 0L);
    k_vm<8, 128, 0><<<dim3(8, 8), 256, 0, stream>>>(h_f, Wf2, fb, 0L);
    k_out<<<dim3(BB, 2), 256, 0, stream>>>(lg, fb, bo2, bf2, out);
}

// Round 3
// 753.210 us; speedup vs baseline: 1.1957x; 1.1957x over previous
//
#include <hip/hip_runtime.h>

// Problem constants
#define BB 64      // batch
#define SS 1024    // symbols (= values = d_model = 1024, all dims equal)
#define NN 1024    // generic K/N dim

// Batched vec-mat with K-split + atomic accumulate, one batch row per y-block.
// C[b, t] += sum_k a[b, k] * W[b*S*S + k*NN + t]
// GATHER=1: a[b,k] = qmask[b] * SMq[b, qidx[b], k]  (walk1 computed on the fly)
// GATHER=0: a[b,k] = A[b*NN + k]
// REV=1: process batches in reverse order (L3-residency heuristic: the tail
//        of the previous streaming pass is still resident in Infinity Cache).
template<int KC, int GATHER, int REV>
__global__ __launch_bounds__(256) void k_walk(const float* __restrict__ A,
                                              const float* __restrict__ W,
                                              float* __restrict__ C,
                                              const int* __restrict__ qidx,
                                              const float* __restrict__ qmask) {
    const int k0 = blockIdx.x * KC;
    const int b  = REV ? (gridDim.y - 1 - blockIdx.y) : blockIdx.y;

    __shared__ float As[KC];
    if (threadIdx.x < KC) {
        float v;
        if (GATHER) {
            int q = qidx[b];
            v = qmask[b] * W[(size_t)b * SS * SS + (size_t)q * SS + k0 + threadIdx.x];
        } else {
            v = A[b * NN + k0 + threadIdx.x];
        }
        As[threadIdx.x] = v;
    }
    __syncthreads();

    const float* Wp = W + (size_t)b * SS * SS + (size_t)k0 * NN + threadIdx.x * 4;
    float acc0 = 0.f, acc1 = 0.f, acc2 = 0.f, acc3 = 0.f;
    for (int k = 0; k < KC; ++k) {
        float4 wv = *(const float4*)(Wp + (size_t)k * NN);
        float a = As[k];
        acc0 = fmaf(a, wv.x, acc0);
        acc1 = fmaf(a, wv.y, acc1);
        acc2 = fmaf(a, wv.z, acc2);
        acc3 = fmaf(a, wv.w, acc3);
    }
    float* c = C + (size_t)b * NN + threadIdx.x * 4;
    unsafeAtomicAdd(c + 0, acc0);
    unsafeAtomicAdd(c + 1, acc1);
    unsafeAtomicAdd(c + 2, acc2);
    unsafeAtomicAdd(c + 3, acc3);
}

// Small skinny GEMM (shared weights), dual-problem via blockIdx.z.
// C[r,t] += sum_k A[r,k] * W[k*NN + t];  ROWS rows/block, K-split + atomics.
template<int ROWS, int KC>
__global__ __launch_bounds__(256) void k_small(const float* __restrict__ A0,
                                               const float* __restrict__ W0,
                                               float* __restrict__ C0,
                                               const float* __restrict__ A1,
                                               const float* __restrict__ W1,
                                               float* __restrict__ C1) {
    const float* A = blockIdx.z ? A1 : A0;
    const float* W = blockIdx.z ? W1 : W0;
    float*       C = blockIdx.z ? C1 : C0;
    const int k0 = blockIdx.x * KC;
    const int r0 = blockIdx.y * ROWS;

    __shared__ float As[ROWS * KC];
    for (int i = threadIdx.x; i < ROWS * KC; i += 256) {
        int r = i / KC, k = i % KC;
        As[i] = A[(r0 + r) * NN + k0 + k];
    }
    __syncthreads();

    const float* Wp = W + (size_t)k0 * NN + threadIdx.x * 4;
    float acc[ROWS][4];
    #pragma unroll
    for (int r = 0; r < ROWS; ++r) {
        acc[r][0] = 0.f; acc[r][1] = 0.f; acc[r][2] = 0.f; acc[r][3] = 0.f;
    }
    for (int k = 0; k < KC; ++k) {
        float4 wv = *(const float4*)(Wp + (size_t)k * NN);
        #pragma unroll
        for (int r = 0; r < ROWS; ++r) {
            float a = As[r * KC + k];
            acc[r][0] = fmaf(a, wv.x, acc[r][0]);
            acc[r][1] = fmaf(a, wv.y, acc[r][1]);
            acc[r][2] = fmaf(a, wv.z, acc[r][2]);
            acc[r][3] = fmaf(a, wv.w, acc[r][3]);
        }
    }
    const int t = threadIdx.x * 4;
    #pragma unroll
    for (int r = 0; r < ROWS; ++r) {
        float* c = C + (size_t)(r0 + r) * NN + t;
        unsafeAtomicAdd(c + 0, acc[r][0]);
        unsafeAtomicAdd(c + 1, acc[r][1]);
        unsafeAtomicAdd(c + 2, acc[r][2]);
        unsafeAtomicAdd(c + 3, acc[r][3]);
    }
}

// Wsum[b,s] = m*SM[b,q,s] (walk1, recomputed) + walk2 + walk3 + m*(s==q)
__global__ void k_wsum(const float* __restrict__ SM,
                       const float* __restrict__ w2, const float* __restrict__ w3,
                       const int* __restrict__ qidx, const float* __restrict__ qmask,
                       float* __restrict__ Wsum) {
    int b = blockIdx.x;
    int q = qidx[b];
    float m = qmask[b];
    const float* row = SM + (size_t)b * SS * SS + (size_t)q * SS;
    int t = threadIdx.x * 4;
    #pragma unroll
    for (int j = 0; j < 4; ++j) {
        int s = t + j;
        float v = m * row[s] + w2[b * SS + s] + w3[b * SS + s];
        if (s == q) v += m;
        Wsum[b * SS + s] = v;
    }
}

// In-place bias + tanh-approx GELU on h0 (y=0) / h1 (y=1)
__global__ void k_biasgelu(float* __restrict__ h0, float* __restrict__ h1,
                           const float* __restrict__ b0, const float* __restrict__ b1) {
    float* h = blockIdx.y ? h1 : h0;
    const float* bias = blockIdx.y ? b1 : b0;
    int b = blockIdx.x;
    int t = threadIdx.x * 4;
    #pragma unroll
    for (int j = 0; j < 4; ++j) {
        int d = t + j;
        float x = h[b * NN + d] + bias[d];
        float c = 0.7978845608028654f * (x + 0.044715f * x * x * x);
        h[b * NN + d] = 0.5f * x * (1.0f + tanhf(c));
    }
}

// d_out = src + bias; y=0: logits (offset 0), y=1: feedback (offset B*N)
__global__ void k_out(const float* __restrict__ lg, const float* __restrict__ fb,
                      const float* __restrict__ bo2, const float* __restrict__ bf2,
                      float* __restrict__ out) {
    int half = blockIdx.y;
    const float* src = half ? fb : lg;
    const float* bias = half ? bf2 : bo2;
    float* dst = out + (size_t)half * BB * NN;
    int b = blockIdx.x;
    int t = threadIdx.x * 4;
    #pragma unroll
    for (int j = 0; j < 4; ++j) {
        int n = t + j;
        dst[b * NN + n] = src[b * NN + n] + bias[n];
    }
}

extern "C" void kernel_launch(void* const* d_in, const int* in_sizes, int n_in,
                              void* d_out, int out_size, void* d_ws, size_t ws_size,
                              hipStream_t stream) {
    const float* MM   = (const float*)d_in[0];   // map_memory  [B,S,V]
    const float* SM   = (const float*)d_in[1];   // step_memory [B,S,S]
    const int*   qidx = (const int*)d_in[2];     // query_idx   [B]
    const float* qmask= (const float*)d_in[3];   // query_mask  [B]
    const float* sb   = (const float*)d_in[4];   // symbol_bank [S,D]
    const float* vb   = (const float*)d_in[5];   // value_bank  [V,D]
    const float* Wo1  = (const float*)d_in[6];
    const float* bo1  = (const float*)d_in[7];
    const float* Wo2  = (const float*)d_in[8];
    const float* bo2  = (const float*)d_in[9];
    const float* Wf1  = (const float*)d_in[10];
    const float* bf1  = (const float*)d_in[11];
    const float* Wf2  = (const float*)d_in[12];
    const float* bf2  = (const float*)d_in[13];
    float* out = (float*)d_out;

    float* ws    = (float*)d_ws;
    // atomic accumulators (must be zeroed), contiguous block of 8 x 64K floats
    float* walk2 = ws;
    float* walk3 = ws + 65536;
    float* accv  = ws + 131072;
    float* gs    = ws + 196608;
    float* h_o   = ws + 262144;
    float* h_f   = ws + 327680;
    float* lg    = ws + 393216;
    float* fb    = ws + 458752;
    float* Wsum  = ws + 524288;   // fully written, no zeroing needed

    hipMemsetAsync(d_ws, 0, 524288 * sizeof(float), stream);

    // walk2 = (m * SM[b,q,:]) @ SM[b]     (gather fused; full SM stream)
    k_walk<64, 1, 0><<<dim3(16, BB), 256, 0, stream>>>(nullptr, SM, walk2, qidx, qmask);
    // walk3 = walk2 @ SM[b]               (reverse order: L3 re-hit)
    k_walk<64, 0, 1><<<dim3(16, BB), 256, 0, stream>>>(walk2, SM, walk3, qidx, qmask);
    // Wsum = walk1 + walk2 + walk3 + one-hot
    k_wsum<<<BB, 256, 0, stream>>>(SM, walk2, walk3, qidx, qmask, Wsum);
    // acc_values = Wsum @ MM[b]           (full MM stream)
    k_walk<64, 0, 0><<<dim3(16, BB), 256, 0, stream>>>(Wsum, MM, accv, qidx, qmask);
    // graph_state = Wsum @ symbol_bank + accv @ value_bank
    k_small<8, 128><<<dim3(8, 8, 2), 256, 0, stream>>>(Wsum, sb, gs, accv, vb, gs);
    // h_o = gs @ Wo1 ; h_f = gs @ Wf1
    k_small<8, 128><<<dim3(8, 8, 2), 256, 0, stream>>>(gs, Wo1, h_o, gs, Wf1, h_f);
    k_biasgelu<<<dim3(BB, 2), 256, 0, stream>>>(h_o, h_f, bo1, bf1);
    // lg = gelu_h_o @ Wo2 ; fb = gelu_h_f @ Wf2
    k_small<8, 128><<<dim3(8, 8, 2), 256, 0, stream>>>(h_o, Wo2, lg, h_f, Wf2, fb);
    k_out<<<dim3(BB, 2), 256, 0, stream>>>(lg, fb, bo2, bf2, out);
}